// Round 7
// baseline (105.317 us; speedup 1.0000x reference)
//
#include <hip/hip_runtime.h>

#define HP 192
#define WP 192
#define NPIX (HP * WP)   // 36864
#define SG 24
#define KSTRU 72         // smK row stride in ushorts: 144 B
#define PSTR 12          // smpi row stride (floats)

__device__ __forceinline__ unsigned int bfpack(float a, float b) {
  unsigned int ua = __float_as_uint(a), ub = __float_as_uint(b);
  ua = (ua + 0x7FFFu + ((ua >> 16) & 1u)) >> 16;   // RTNE bf16
  ub = (ub + 0x7FFFu + ((ub >> 16) & 1u)) >> 16;
  return ua | (ub << 16);
}

// ---------------- Kernel 1: QKV projection -----------------------------------
__global__ __launch_bounds__(256) void qkv_kernel(
    const float* __restrict__ x,
    const float* __restrict__ w_qk,
    const float* __restrict__ w_v,
    float* __restrict__ qb, float* __restrict__ kb, float* __restrict__ vb) {
  const int jb = blockIdx.y;  // 0..11
  const int pix = blockIdx.x * 256 + threadIdx.x;
  float xv[64];
#pragma unroll
  for (int c = 0; c < 64; ++c) xv[c] = x[c * NPIX + pix];
  float acc[16];
#pragma unroll
  for (int j = 0; j < 16; ++j) acc[j] = 0.f;
  const int j0 = jb * 16;
  if (jb < 8) {
#pragma unroll
    for (int c = 0; c < 64; ++c) {
      const float* wr = w_qk + c * 128 + j0;
      const float xc = xv[c];
#pragma unroll
      for (int j = 0; j < 16; ++j) acc[j] = fmaf(xc, wr[j], acc[j]);
    }
  } else {
#pragma unroll
    for (int c = 0; c < 64; ++c) {
      const float* wr = w_v + c * 64 + (j0 - 128);
      const float xc = xv[c];
#pragma unroll
      for (int j = 0; j < 16; ++j) acc[j] = fmaf(xc, wr[j], acc[j]);
    }
  }
  float* dst;
  float mul = 1.0f;
  if (jb < 4) {
    dst = qb + (size_t)pix * 64 + j0;
    mul = 0.25f;  // hd^-0.5, hd=16
  } else if (jb < 8) {
    dst = kb + (size_t)pix * 64 + (j0 - 64);
  } else {
    dst = vb + (size_t)pix * 64 + (j0 - 128);
  }
#pragma unroll
  for (int j = 0; j < 16; ++j) dst[j] = acc[j] * mul;
}

// ---------------- Kernel 2: attention ----------------------------------------
// Block = 512 threads = 64 px x 4 heads x 2 SPLITS. split = lane bit 0:
// the 49 neighbors are interleaved across the lane pair (n = 2i+split), and
// partial {S, D9} / o[16] are combined with __shfl_xor(.,1). Doubles total
// waves (4608 -> 4.5/SIMD) to hide LDS/global latency.
// K staged in LDS bf16 (28.2 KB) + pi f32 (9.4 KB); V read from global.
__global__ __launch_bounds__(512) void attn_kernel(
    const float* __restrict__ qb, const float* __restrict__ kb,
    const float* __restrict__ vb, const float* __restrict__ sims,
    float* __restrict__ pre) {
  __shared__ __align__(16) unsigned short smK[196 * KSTRU];
  __shared__ __align__(16) float smpi[196 * PSTR];
  const int tile = blockIdx.x;
  const int th = tile / 24, tw = tile % 24;
  const int rowBase = th * 8 - 3, colBase = tw * 8 - 3;
  const int tid = threadIdx.x;

  // ---- stage K tile: global f32 -> bf16 LDS (8-ch chunks) ----
  for (int i = tid; i < 196 * 8; i += 512) {
    const int loc = i >> 3, d8 = i & 7;
    const int rl = loc / 14, cl = loc - rl * 14;
    const int r = rowBase + rl, c = colBase + cl;
    uint4 kw4 = make_uint4(0u, 0u, 0u, 0u);
    if (r >= 0 && r < HP && c >= 0 && c < WP) {
      const size_t base = ((size_t)(r * WP + c)) * 64 + (d8 << 3);
      const float4 ka = *(const float4*)(kb + base);
      const float4 kb8 = *(const float4*)(kb + base + 4);
      kw4.x = bfpack(ka.x, ka.y);
      kw4.y = bfpack(ka.z, ka.w);
      kw4.z = bfpack(kb8.x, kb8.y);
      kw4.w = bfpack(kb8.z, kb8.w);
    }
    *(uint4*)(smK + loc * KSTRU + (d8 << 3)) = kw4;
  }
  // ---- stage pi table ----
  for (int i = tid; i < 196 * 9; i += 512) {
    const int loc = i / 9, s = i - loc * 9;
    const int rl = loc / 14, cl = loc - rl * 14;
    const int r = rowBase + rl, c = colBase + cl;
    const int dh = s / 3, dw = s - dh * 3;
    const int shi = th + dh - 1, swj = tw + dw - 1;
    float val = 0.f;
    if (shi >= 0 && shi < SG && swj >= 0 && swj < SG && r >= 0 && r < HP &&
        c >= 0 && c < WP)
      val = sims[((size_t)(r * WP + c)) * (SG * SG) + shi * SG + swj];
    smpi[loc * PSTR + s] = val;
  }
  __syncthreads();

  const int split = tid & 1;
  const int head = (tid >> 1) & 3;
  const int pl = tid >> 3;
  const int py = pl >> 3, px = pl & 7;
  const int h = th * 8 + py, w = tw * 8 + px;
  const int pix = h * WP + w;
  int hs = h - 3;
  hs = hs < 0 ? 0 : (hs > HP - 7 ? HP - 7 : hs);
  int wsb = w - 3;
  wsb = wsb < 0 ? 0 : (wsb > WP - 7 ? WP - 7 : wsb);
  const int rl0 = hs - rowBase;   // 0..7
  const int cl0 = wsb - colBase;  // 0..7
  const int hq = head << 4;       // head channel base

  const float4* qp = (const float4*)(qb + (size_t)pix * 64 + hq);
  const float4 q0 = qp[0], q1 = qp[1], q2 = qp[2], q3 = qp[3];

#define ACC2T(tn, u, qa, qb)                            \
  tn = fmaf(__uint_as_float((u) << 16), (qa), tn);      \
  tn = fmaf(__uint_as_float((u) & 0xFFFF0000u), (qb), tn);

#define DOT16(t, kp)                                    \
  {                                                     \
    const uint4 ka = *(const uint4*)(kp);               \
    const uint4 kc = *(const uint4*)((kp) + 8);         \
    float t0 = 0.f, t1 = 0.f, t2 = 0.f, t3 = 0.f;       \
    ACC2T(t0, ka.x, q0.x, q0.y)                         \
    ACC2T(t0, ka.y, q0.z, q0.w)                         \
    ACC2T(t1, ka.z, q1.x, q1.y)                         \
    ACC2T(t1, ka.w, q1.z, q1.w)                         \
    ACC2T(t2, kc.x, q2.x, q2.y)                         \
    ACC2T(t2, kc.y, q2.z, q2.w)                         \
    ACC2T(t3, kc.z, q3.x, q3.y)                         \
    ACC2T(t3, kc.w, q3.z, q3.w)                         \
    t = (t0 + t1) + (t2 + t3);                          \
  }

  // ---- pass 1: this lane's ~25 neighbors -> partial S, D9 ----
  float D9[9];
#pragma unroll
  for (int s = 0; s < 9; ++s) D9[s] = 0.f;
  float S = 0.f;
#pragma unroll 5
  for (int i = 0; i < 25; ++i) {
    const int n = (i << 1) | split;
    if (n < 49) {
      const int kh = (n * 37) >> 8;   // exact n/7 for n<49
      const int kw = n - kh * 7;
      const int loc = (rl0 + kh) * 14 + cl0 + kw;
      float t;
      DOT16(t, smK + loc * KSTRU + hq)
      const float e = __expf(t);
      S += e;
      const float* pp = smpi + loc * PSTR;
      const float4 p0 = *(const float4*)pp;
      const float4 p1 = *(const float4*)(pp + 4);
      const float p8 = pp[8];
      D9[0] = fmaf(e, p0.x, D9[0]);
      D9[1] = fmaf(e, p0.y, D9[1]);
      D9[2] = fmaf(e, p0.z, D9[2]);
      D9[3] = fmaf(e, p0.w, D9[3]);
      D9[4] = fmaf(e, p1.x, D9[4]);
      D9[5] = fmaf(e, p1.y, D9[5]);
      D9[6] = fmaf(e, p1.z, D9[6]);
      D9[7] = fmaf(e, p1.w, D9[7]);
      D9[8] = fmaf(e, p8, D9[8]);
    }
  }
  // ---- combine lane pair ----
  S += __shfl_xor(S, 1);
#pragma unroll
  for (int s = 0; s < 9; ++s) D9[s] += __shfl_xor(D9[s], 1);

  // ---- coef_s = ws[s] / (D[s] + 1e-10*S) ----
  float coef[9];
  {
    const float* pp = smpi + ((h - rowBase) * 14 + (w - colBase)) * PSTR;
    const float4 p0 = *(const float4*)pp;
    const float4 p1 = *(const float4*)(pp + 4);
    const float p8 = pp[8];
    const float epsS = 1e-10f * S;
    coef[0] = p0.x / (D9[0] + epsS);
    coef[1] = p0.y / (D9[1] + epsS);
    coef[2] = p0.z / (D9[2] + epsS);
    coef[3] = p0.w / (D9[3] + epsS);
    coef[4] = p1.x / (D9[4] + epsS);
    coef[5] = p1.y / (D9[5] + epsS);
    coef[6] = p1.z / (D9[6] + epsS);
    coef[7] = p1.w / (D9[7] + epsS);
    coef[8] = p8 / (D9[8] + epsS);
  }

  // ---- pass 2: recompute e; a2 = e*(coef.pi); o += a2 * v(global) ----
  float4 o0 = make_float4(0.f, 0.f, 0.f, 0.f);
  float4 o1 = make_float4(0.f, 0.f, 0.f, 0.f);
  float4 o2 = make_float4(0.f, 0.f, 0.f, 0.f);
  float4 o3 = make_float4(0.f, 0.f, 0.f, 0.f);
#pragma unroll 5
  for (int i = 0; i < 25; ++i) {
    const int n = (i << 1) | split;
    if (n < 49) {
      const int kh = (n * 37) >> 8;
      const int kw = n - kh * 7;
      const int loc = (rl0 + kh) * 14 + cl0 + kw;
      float t;
      DOT16(t, smK + loc * KSTRU + hq)
      const float e = __expf(t);
      const float* pp = smpi + loc * PSTR;
      const float4 p0 = *(const float4*)pp;
      const float4 p1 = *(const float4*)(pp + 4);
      const float p8 = pp[8];
      const float tca = coef[0] * p0.x + coef[1] * p0.y;
      const float tcb = coef[2] * p0.z + coef[3] * p0.w;
      const float tcc = coef[4] * p1.x + coef[5] * p1.y;
      const float tcd = coef[6] * p1.z + coef[7] * p1.w;
      const float tc = ((tca + tcb) + (tcc + tcd)) + coef[8] * p8;
      const float a2 = e * tc;
      const float* vp = vb + (size_t)((hs + kh) * WP + wsb + kw) * 64 + hq;
      const float4 v0 = *(const float4*)(vp);
      const float4 v1 = *(const float4*)(vp + 4);
      const float4 v2 = *(const float4*)(vp + 8);
      const float4 v3 = *(const float4*)(vp + 12);
      o0.x = fmaf(a2, v0.x, o0.x);
      o0.y = fmaf(a2, v0.y, o0.y);
      o0.z = fmaf(a2, v0.z, o0.z);
      o0.w = fmaf(a2, v0.w, o0.w);
      o1.x = fmaf(a2, v1.x, o1.x);
      o1.y = fmaf(a2, v1.y, o1.y);
      o1.z = fmaf(a2, v1.z, o1.z);
      o1.w = fmaf(a2, v1.w, o1.w);
      o2.x = fmaf(a2, v2.x, o2.x);
      o2.y = fmaf(a2, v2.y, o2.y);
      o2.z = fmaf(a2, v2.z, o2.z);
      o2.w = fmaf(a2, v2.w, o2.w);
      o3.x = fmaf(a2, v3.x, o3.x);
      o3.y = fmaf(a2, v3.y, o3.y);
      o3.z = fmaf(a2, v3.z, o3.z);
      o3.w = fmaf(a2, v3.w, o3.w);
    }
  }
#undef DOT16
#undef ACC2T
  // ---- combine lane pair: each writes half the channels ----
  o0.x += __shfl_xor(o0.x, 1); o0.y += __shfl_xor(o0.y, 1);
  o0.z += __shfl_xor(o0.z, 1); o0.w += __shfl_xor(o0.w, 1);
  o1.x += __shfl_xor(o1.x, 1); o1.y += __shfl_xor(o1.y, 1);
  o1.z += __shfl_xor(o1.z, 1); o1.w += __shfl_xor(o1.w, 1);
  o2.x += __shfl_xor(o2.x, 1); o2.y += __shfl_xor(o2.y, 1);
  o2.z += __shfl_xor(o2.z, 1); o2.w += __shfl_xor(o2.w, 1);
  o3.x += __shfl_xor(o3.x, 1); o3.y += __shfl_xor(o3.y, 1);
  o3.z += __shfl_xor(o3.z, 1); o3.w += __shfl_xor(o3.w, 1);
  float4* op = (float4*)(pre + (size_t)pix * 64 + hq);
  if (split == 0) {
    op[0] = o0;
    op[1] = o1;
  } else {
    op[2] = o2;
    op[3] = o3;
  }
}

// ---------------- Kernel 3: output projection --------------------------------
// grid (144, 8): jb picks 8 output channels; 1152 blocks (4.5 waves/SIMD).
__global__ __launch_bounds__(256) void proj_kernel(
    const float* __restrict__ pre, const float* __restrict__ w_proj,
    float* __restrict__ out) {
  const int jb = blockIdx.y;  // 0..7
  const int pix = blockIdx.x * 256 + threadIdx.x;
  float xv[64];
  const float4* pp = (const float4*)(pre + (size_t)pix * 64);
#pragma unroll
  for (int i = 0; i < 16; ++i) {
    const float4 t = pp[i];
    xv[i * 4 + 0] = t.x;
    xv[i * 4 + 1] = t.y;
    xv[i * 4 + 2] = t.z;
    xv[i * 4 + 3] = t.w;
  }
  float acc[8];
#pragma unroll
  for (int j = 0; j < 8; ++j) acc[j] = 0.f;
  const int j0 = jb * 8;
#pragma unroll
  for (int c = 0; c < 64; ++c) {
    const float* wr = w_proj + c * 64 + j0;
    const float xc = xv[c];
#pragma unroll
    for (int j = 0; j < 8; ++j) acc[j] = fmaf(xc, wr[j], acc[j]);
  }
#pragma unroll
  for (int j = 0; j < 8; ++j) out[(size_t)(j0 + j) * NPIX + pix] = acc[j];
}

extern "C" void kernel_launch(void* const* d_in, const int* in_sizes, int n_in,
                              void* d_out, int out_size, void* d_ws,
                              size_t ws_size, hipStream_t stream) {
  const float* x = (const float*)d_in[0];
  const float* sims = (const float*)d_in[1];
  const float* w_qk = (const float*)d_in[2];
  const float* w_v = (const float*)d_in[3];
  const float* w_proj = (const float*)d_in[4];
  float* out = (float*)d_out;

  float* qb = (float*)d_ws;
  float* kb = qb + (size_t)NPIX * 64;
  float* vb = kb + (size_t)NPIX * 64;
  float* pre = vb + (size_t)NPIX * 64;

  qkv_kernel<<<dim3(144, 12), 256, 0, stream>>>(x, w_qk, w_v, qb, kb, vb);
  attn_kernel<<<dim3(576), 512, 0, stream>>>(qb, kb, vb, sims, pre);
  proj_kernel<<<dim3(144, 8), 256, 0, stream>>>(pre, w_proj, out);
}

// Round 8
// 92.291 us; speedup vs baseline: 1.1411x; 1.1411x over previous
//
#include <hip/hip_runtime.h>

#define HP 192
#define WP 192
#define NPIX (HP * WP)   // 36864
#define SG 24
#define KSTRU 72         // smK row stride in ushorts (f16): 144 B
#define PSTR 12          // smpi row stride (floats)
#define PRESTR 65        // preLds row stride (floats): 65 -> conflict-free b32

typedef _Float16 h2 __attribute__((ext_vector_type(2)));

__device__ __forceinline__ unsigned int h2pack(float a, float b) {
  h2 r;
  r[0] = (_Float16)a;
  r[1] = (_Float16)b;
  return __builtin_bit_cast(unsigned int, r);
}
__device__ __forceinline__ h2 ash2(unsigned int u) {
  return __builtin_bit_cast(h2, u);
}

// ---------------- Kernel 1: QKV projection -----------------------------------
__global__ __launch_bounds__(256) void qkv_kernel(
    const float* __restrict__ x,
    const float* __restrict__ w_qk,
    const float* __restrict__ w_v,
    float* __restrict__ qb, float* __restrict__ kb, float* __restrict__ vb) {
  const int jb = blockIdx.y;  // 0..11
  const int pix = blockIdx.x * 256 + threadIdx.x;
  float xv[64];
#pragma unroll
  for (int c = 0; c < 64; ++c) xv[c] = x[c * NPIX + pix];
  float acc[16];
#pragma unroll
  for (int j = 0; j < 16; ++j) acc[j] = 0.f;
  const int j0 = jb * 16;
  if (jb < 8) {
#pragma unroll
    for (int c = 0; c < 64; ++c) {
      const float* wr = w_qk + c * 128 + j0;
      const float xc = xv[c];
#pragma unroll
      for (int j = 0; j < 16; ++j) acc[j] = fmaf(xc, wr[j], acc[j]);
    }
  } else {
#pragma unroll
    for (int c = 0; c < 64; ++c) {
      const float* wr = w_v + c * 64 + (j0 - 128);
      const float xc = xv[c];
#pragma unroll
      for (int j = 0; j < 16; ++j) acc[j] = fmaf(xc, wr[j], acc[j]);
    }
  }
  float* dst;
  float mul = 1.0f;
  if (jb < 4) {
    dst = qb + (size_t)pix * 64 + j0;
    mul = 0.25f;  // hd^-0.5, hd=16
  } else if (jb < 8) {
    dst = kb + (size_t)pix * 64 + (j0 - 64);
  } else {
    dst = vb + (size_t)pix * 64 + (j0 - 128);
  }
#pragma unroll
  for (int j = 0; j < 16; ++j) dst[j] = acc[j] * mul;
}

// ---------------- Kernel 2: attention + fused output projection --------------
// Block = 512 threads = 64 px x 4 heads x 2 splits (neighbors interleaved
// across the lane pair, combined with __shfl_xor(.,1)).
// K staged in LDS as f16; dot products via v_dot2_f32_f16 (fdot2): 8 instrs
// per 16-ch dot, no unpack. V read from global (L2-hot).
// After PV, per-pixel 64-ch result goes to preLds and the output projection
// runs in-block (w_proj staged in LDS), writing `out` directly.
__global__ __launch_bounds__(512) void attn_kernel(
    const float* __restrict__ qb, const float* __restrict__ kb,
    const float* __restrict__ vb, const float* __restrict__ sims,
    const float* __restrict__ w_proj, float* __restrict__ out) {
  __shared__ __align__(16) unsigned short smK[196 * KSTRU];
  __shared__ __align__(16) float smpi[196 * PSTR];
  __shared__ __align__(16) float preLds[64 * PRESTR];
  __shared__ __align__(16) float wLds[64 * 64];
  const int tile = blockIdx.x;
  const int th = tile / 24, tw = tile % 24;
  const int rowBase = th * 8 - 3, colBase = tw * 8 - 3;
  const int tid = threadIdx.x;

  // ---- stage w_proj (16 KB, coalesced) ----
#pragma unroll
  for (int i = 0; i < 8; ++i) wLds[i * 512 + tid] = w_proj[i * 512 + tid];

  // ---- stage K tile: global f32 -> f16 LDS (8-ch chunks) ----
  for (int i = tid; i < 196 * 8; i += 512) {
    const int loc = i >> 3, d8 = i & 7;
    const int rl = loc / 14, cl = loc - rl * 14;
    const int r = rowBase + rl, c = colBase + cl;
    uint4 kw4 = make_uint4(0u, 0u, 0u, 0u);
    if (r >= 0 && r < HP && c >= 0 && c < WP) {
      const size_t base = ((size_t)(r * WP + c)) * 64 + (d8 << 3);
      const float4 ka = *(const float4*)(kb + base);
      const float4 kb8 = *(const float4*)(kb + base + 4);
      kw4.x = h2pack(ka.x, ka.y);
      kw4.y = h2pack(ka.z, ka.w);
      kw4.z = h2pack(kb8.x, kb8.y);
      kw4.w = h2pack(kb8.z, kb8.w);
    }
    *(uint4*)(smK + loc * KSTRU + (d8 << 3)) = kw4;
  }
  // ---- stage pi table ----
  for (int i = tid; i < 196 * 9; i += 512) {
    const int loc = i / 9, s = i - loc * 9;
    const int rl = loc / 14, cl = loc - rl * 14;
    const int r = rowBase + rl, c = colBase + cl;
    const int dh = s / 3, dw = s - dh * 3;
    const int shi = th + dh - 1, swj = tw + dw - 1;
    float val = 0.f;
    if (shi >= 0 && shi < SG && swj >= 0 && swj < SG && r >= 0 && r < HP &&
        c >= 0 && c < WP)
      val = sims[((size_t)(r * WP + c)) * (SG * SG) + shi * SG + swj];
    smpi[loc * PSTR + s] = val;
  }
  __syncthreads();

  const int split = tid & 1;
  const int head = (tid >> 1) & 3;
  const int pl = tid >> 3;  // pixel-in-tile 0..63
  const int py = pl >> 3, px = pl & 7;
  const int h = th * 8 + py, w = tw * 8 + px;
  const int pix = h * WP + w;
  int hs = h - 3;
  hs = hs < 0 ? 0 : (hs > HP - 7 ? HP - 7 : hs);
  int wsb = w - 3;
  wsb = wsb < 0 ? 0 : (wsb > WP - 7 ? WP - 7 : wsb);
  const int rl0 = hs - rowBase;   // 0..7
  const int cl0 = wsb - colBase;  // 0..7
  const int hq = head << 4;       // head channel base (halves/floats)

  // q: load f32, pack to 8x h2
  const float4* qp = (const float4*)(qb + (size_t)pix * 64 + hq);
  const float4 q0 = qp[0], q1 = qp[1], q2 = qp[2], q3 = qp[3];
  const h2 qh0 = ash2(h2pack(q0.x, q0.y)), qh1 = ash2(h2pack(q0.z, q0.w));
  const h2 qh2 = ash2(h2pack(q1.x, q1.y)), qh3 = ash2(h2pack(q1.z, q1.w));
  const h2 qh4 = ash2(h2pack(q2.x, q2.y)), qh5 = ash2(h2pack(q2.z, q2.w));
  const h2 qh6 = ash2(h2pack(q3.x, q3.y)), qh7 = ash2(h2pack(q3.z, q3.w));

#define DOT8(t, kp)                                           \
  {                                                           \
    const uint4 ka = *(const uint4*)(kp);                     \
    const uint4 kc = *(const uint4*)((kp) + 8);               \
    float t0 = 0.f, t1 = 0.f;                                 \
    t0 = __builtin_amdgcn_fdot2(ash2(ka.x), qh0, t0, false);  \
    t0 = __builtin_amdgcn_fdot2(ash2(ka.y), qh1, t0, false);  \
    t0 = __builtin_amdgcn_fdot2(ash2(ka.z), qh2, t0, false);  \
    t0 = __builtin_amdgcn_fdot2(ash2(ka.w), qh3, t0, false);  \
    t1 = __builtin_amdgcn_fdot2(ash2(kc.x), qh4, t1, false);  \
    t1 = __builtin_amdgcn_fdot2(ash2(kc.y), qh5, t1, false);  \
    t1 = __builtin_amdgcn_fdot2(ash2(kc.z), qh6, t1, false);  \
    t1 = __builtin_amdgcn_fdot2(ash2(kc.w), qh7, t1, false);  \
    t = t0 + t1;                                              \
  }

  // ---- pass 1: this lane's ~25 neighbors -> partial S, D9 ----
  float D9[9];
#pragma unroll
  for (int s = 0; s < 9; ++s) D9[s] = 0.f;
  float S = 0.f;
#pragma unroll 5
  for (int i = 0; i < 25; ++i) {
    const int n = (i << 1) | split;
    if (n < 49) {
      const int kh = (n * 37) >> 8;   // exact n/7 for n<49
      const int kw = n - kh * 7;
      const int loc = (rl0 + kh) * 14 + cl0 + kw;
      float t;
      DOT8(t, smK + loc * KSTRU + hq)
      const float e = __expf(t);
      S += e;
      const float* pp = smpi + loc * PSTR;
      const float4 p0 = *(const float4*)pp;
      const float4 p1 = *(const float4*)(pp + 4);
      const float p8 = pp[8];
      D9[0] = fmaf(e, p0.x, D9[0]);
      D9[1] = fmaf(e, p0.y, D9[1]);
      D9[2] = fmaf(e, p0.z, D9[2]);
      D9[3] = fmaf(e, p0.w, D9[3]);
      D9[4] = fmaf(e, p1.x, D9[4]);
      D9[5] = fmaf(e, p1.y, D9[5]);
      D9[6] = fmaf(e, p1.z, D9[6]);
      D9[7] = fmaf(e, p1.w, D9[7]);
      D9[8] = fmaf(e, p8, D9[8]);
    }
  }
  S += __shfl_xor(S, 1);
#pragma unroll
  for (int s = 0; s < 9; ++s) D9[s] += __shfl_xor(D9[s], 1);

  // ---- coef_s = ws[s] / (D[s] + 1e-10*S) ----
  float coef[9];
  {
    const float* pp = smpi + ((h - rowBase) * 14 + (w - colBase)) * PSTR;
    const float4 p0 = *(const float4*)pp;
    const float4 p1 = *(const float4*)(pp + 4);
    const float p8 = pp[8];
    const float epsS = 1e-10f * S;
    coef[0] = p0.x / (D9[0] + epsS);
    coef[1] = p0.y / (D9[1] + epsS);
    coef[2] = p0.z / (D9[2] + epsS);
    coef[3] = p0.w / (D9[3] + epsS);
    coef[4] = p1.x / (D9[4] + epsS);
    coef[5] = p1.y / (D9[5] + epsS);
    coef[6] = p1.z / (D9[6] + epsS);
    coef[7] = p1.w / (D9[7] + epsS);
    coef[8] = p8 / (D9[8] + epsS);
  }

  // ---- pass 2: recompute t via fdot2; a2 = e*(coef.pi); o += a2*v ----
  float4 o0 = make_float4(0.f, 0.f, 0.f, 0.f);
  float4 o1 = make_float4(0.f, 0.f, 0.f, 0.f);
  float4 o2 = make_float4(0.f, 0.f, 0.f, 0.f);
  float4 o3 = make_float4(0.f, 0.f, 0.f, 0.f);
#pragma unroll 5
  for (int i = 0; i < 25; ++i) {
    const int n = (i << 1) | split;
    if (n < 49) {
      const int kh = (n * 37) >> 8;
      const int kw = n - kh * 7;
      const int loc = (rl0 + kh) * 14 + cl0 + kw;
      float t;
      DOT8(t, smK + loc * KSTRU + hq)
      const float e = __expf(t);
      const float* pp = smpi + loc * PSTR;
      const float4 p0 = *(const float4*)pp;
      const float4 p1 = *(const float4*)(pp + 4);
      const float p8 = pp[8];
      const float tca = coef[0] * p0.x + coef[1] * p0.y;
      const float tcb = coef[2] * p0.z + coef[3] * p0.w;
      const float tcc = coef[4] * p1.x + coef[5] * p1.y;
      const float tcd = coef[6] * p1.z + coef[7] * p1.w;
      const float tc = ((tca + tcb) + (tcc + tcd)) + coef[8] * p8;
      const float a2 = e * tc;
      const float* vp = vb + (size_t)((hs + kh) * WP + wsb + kw) * 64 + hq;
      const float4 v0 = *(const float4*)(vp);
      const float4 v1 = *(const float4*)(vp + 4);
      const float4 v2 = *(const float4*)(vp + 8);
      const float4 v3 = *(const float4*)(vp + 12);
      o0.x = fmaf(a2, v0.x, o0.x);
      o0.y = fmaf(a2, v0.y, o0.y);
      o0.z = fmaf(a2, v0.z, o0.z);
      o0.w = fmaf(a2, v0.w, o0.w);
      o1.x = fmaf(a2, v1.x, o1.x);
      o1.y = fmaf(a2, v1.y, o1.y);
      o1.z = fmaf(a2, v1.z, o1.z);
      o1.w = fmaf(a2, v1.w, o1.w);
      o2.x = fmaf(a2, v2.x, o2.x);
      o2.y = fmaf(a2, v2.y, o2.y);
      o2.z = fmaf(a2, v2.z, o2.z);
      o2.w = fmaf(a2, v2.w, o2.w);
      o3.x = fmaf(a2, v3.x, o3.x);
      o3.y = fmaf(a2, v3.y, o3.y);
      o3.z = fmaf(a2, v3.z, o3.z);
      o3.w = fmaf(a2, v3.w, o3.w);
    }
  }
#undef DOT8

  // ---- combine lane pair; write this (px, head)'s channels to preLds ----
  o0.x += __shfl_xor(o0.x, 1); o0.y += __shfl_xor(o0.y, 1);
  o0.z += __shfl_xor(o0.z, 1); o0.w += __shfl_xor(o0.w, 1);
  o1.x += __shfl_xor(o1.x, 1); o1.y += __shfl_xor(o1.y, 1);
  o1.z += __shfl_xor(o1.z, 1); o1.w += __shfl_xor(o1.w, 1);
  o2.x += __shfl_xor(o2.x, 1); o2.y += __shfl_xor(o2.y, 1);
  o2.z += __shfl_xor(o2.z, 1); o2.w += __shfl_xor(o2.w, 1);
  o3.x += __shfl_xor(o3.x, 1); o3.y += __shfl_xor(o3.y, 1);
  o3.z += __shfl_xor(o3.z, 1); o3.w += __shfl_xor(o3.w, 1);
  {
    float* pw = preLds + pl * PRESTR + hq + split * 8;
    const float4 wlo = split ? o2 : o0;
    const float4 whi = split ? o3 : o1;
    pw[0] = wlo.x; pw[1] = wlo.y; pw[2] = wlo.z; pw[3] = wlo.w;
    pw[4] = whi.x; pw[5] = whi.y; pw[6] = whi.z; pw[7] = whi.w;
  }
  __syncthreads();

  // ---- fused output projection: thread = (jb2 = tid>>6, px2 = tid&63) ----
  const int jb2 = tid >> 6;     // wave-uniform
  const int px2 = tid & 63;
  const int j0 = jb2 * 8;
  const int opix = (th * 8 + (px2 >> 3)) * WP + tw * 8 + (px2 & 7);
  float acc[8];
#pragma unroll
  for (int j = 0; j < 8; ++j) acc[j] = 0.f;
  const float* prow = preLds + px2 * PRESTR;
#pragma unroll 8
  for (int c = 0; c < 64; ++c) {
    const float xc = prow[c];
    const float4 w0 = *(const float4*)(wLds + c * 64 + j0);
    const float4 w1 = *(const float4*)(wLds + c * 64 + j0 + 4);
    acc[0] = fmaf(xc, w0.x, acc[0]);
    acc[1] = fmaf(xc, w0.y, acc[1]);
    acc[2] = fmaf(xc, w0.z, acc[2]);
    acc[3] = fmaf(xc, w0.w, acc[3]);
    acc[4] = fmaf(xc, w1.x, acc[4]);
    acc[5] = fmaf(xc, w1.y, acc[5]);
    acc[6] = fmaf(xc, w1.z, acc[6]);
    acc[7] = fmaf(xc, w1.w, acc[7]);
  }
#pragma unroll
  for (int j = 0; j < 8; ++j) out[(size_t)(j0 + j) * NPIX + opix] = acc[j];
}

extern "C" void kernel_launch(void* const* d_in, const int* in_sizes, int n_in,
                              void* d_out, int out_size, void* d_ws,
                              size_t ws_size, hipStream_t stream) {
  const float* x = (const float*)d_in[0];
  const float* sims = (const float*)d_in[1];
  const float* w_qk = (const float*)d_in[2];
  const float* w_v = (const float*)d_in[3];
  const float* w_proj = (const float*)d_in[4];
  float* out = (float*)d_out;

  float* qb = (float*)d_ws;
  float* kb = qb + (size_t)NPIX * 64;
  float* vb = kb + (size_t)NPIX * 64;

  qkv_kernel<<<dim3(144, 12), 256, 0, stream>>>(x, w_qk, w_v, qb, kb, vb);
  attn_kernel<<<dim3(576), 512, 0, stream>>>(qb, kb, vb, sims, w_proj, out);
}